// Round 3
// baseline (165.826 us; speedup 1.0000x reference)
//
#include <hip/hip_runtime.h>
#include <math.h>

#define L_C 1024
#define B_C 32
#define F_C 24
#define S_C 12
#define N_C (L_C*B_C)   // 32768
#define DWIN 20
#define GRID 768        // persistent blocks: 3 per CU (LDS-limited)
#define NGRP (N_C/4)    // 8192 groups of 4 n (1 wave per n)

// ---------------------------------------------------------------------------
// Kernel A: windowed Gaussian message passing (tail beyond d=20 < 1e-21).
// ---------------------------------------------------------------------------
__global__ void msg_kernel(const float* __restrict__ x, float* __restrict__ mp,
                           float* __restrict__ mf, int C) {
    int idx = blockIdx.x * 256 + threadIdx.x;
    int stride = B_C * C;
    int total = N_C * C;
    if (idx >= total) return;
    int t = idx / stride;
    float accp = 0.f, accf = 0.f;
    #pragma unroll
    for (int d = 1; d <= DWIN; ++d) {
        float w = expf(-0.125f * (float)(d * d));
        if (t >= d)        accp += w * x[idx - d * stride];
        if (t + d < L_C)   accf += w * x[idx + d * stride];
    }
    mp[idx] = accp / fmaxf((float)t, 1.0f);
    mf[idx] = accf / fmaxf((float)(L_C - 1 - t), 1.0f);
}

__device__ inline float segred_max(float v) {
    #pragma unroll
    for (int o = 16; o >= 1; o >>= 1) v = fmaxf(v, __shfl_xor(v, o, 32));
    return v;
}
__device__ inline float segred_sum(float v) {
    #pragma unroll
    for (int o = 16; o >= 1; o >>= 1) v += __shfl_xor(v, o, 32);
    return v;
}

// ---------------------------------------------------------------------------
// Kernel B v3: PERSISTENT fused kernel, 2-deep software pipeline.
// Block = 4 waves = 4 n per group; each block loops over groups bid+it*GRID.
// While computing group i from LDS buf[cur], group i+1's data sits in regs
// (loads issued one full compute-phase earlier) -> memory always in flight.
//
// LDS buffer layout (float4 units, per buffer 1680 f4 = 26880 B, x2 buffers):
//   FF  [0,672)    4n x 24 rows, stride 28 floats (padded: 3-way b128 rows)
//   FS  [672,960)  4n x 288 floats linear (rows of 12)
//   FST [960,1248) linear
//   SFT [1248,1536) linear (12x24, stride 24)
//   SS  [1536,1680) linear
// Staging item space (f4 index i in [0,1584), global read order):
//   FF 576 | FS 288 | FST 288 | SFT 288 | SS 144
// ---------------------------------------------------------------------------
__global__ __launch_bounds__(256, 3) void fuse_kernel(
    const float* __restrict__ f,  const float* __restrict__ s,
    const float* __restrict__ fs, const float* __restrict__ ff,
    const float* __restrict__ ss, const float* __restrict__ fst,
    const float* __restrict__ sft,
    const int* __restrict__ fl, const int* __restrict__ sl,
    const int* __restrict__ yl, const int* __restrict__ y2f,
    const int* __restrict__ y2s,
    const float* __restrict__ fmp, const float* __restrict__ fmf,
    const float* __restrict__ smp, const float* __restrict__ smf,
    float* __restrict__ outf, float* __restrict__ outs,
    float* __restrict__ part)
{
    __shared__ float4 L4[2*1680];   // 53760 B
    float* Lf = (float*)L4;

    const int tid = threadIdx.x;
    const int bid = blockIdx.x;
    const int w    = tid >> 6;
    const int lane = tid & 63;

    // ---- prologue: per-thread staging table (7 items, fully unrolled) ----
    const float4* p[7];
    int step[7], ldsoff[7];
    bool act[7];
    #pragma unroll
    for (int j = 0; j < 7; ++j) {
        int i = tid + 256*j;
        act[j] = (i < 1584);
        int ii = act[j] ? i : 0;
        const float4* pp; int st, lo;
        if (ii < 576) {            // FF: pad rows to stride 28 (7 f4)
            int n = ii/144, rm = ii - n*144, r = rm/6, c = rm - r*6;
            pp = (const float4*)ff + (size_t)bid*576 + ii;
            st = 576*GRID; lo = n*168 + r*7 + c;
        } else if (ii < 864) {
            int k = ii - 576;
            pp = (const float4*)fs + (size_t)bid*288 + k;
            st = 288*GRID; lo = 672 + k;
        } else if (ii < 1152) {
            int k = ii - 864;
            pp = (const float4*)fst + (size_t)bid*288 + k;
            st = 288*GRID; lo = 960 + k;
        } else if (ii < 1440) {
            int k = ii - 1152;
            pp = (const float4*)sft + (size_t)bid*288 + k;
            st = 288*GRID; lo = 1248 + k;
        } else {
            int k = ii - 1440;
            pp = (const float4*)ss + (size_t)bid*144 + k;
            st = 144*GRID; lo = 1536 + k;
        }
        p[j] = pp; step[j] = st; ldsoff[j] = lo;
    }

    float4 r[7];
    const int niter = (NGRP - bid + GRID - 1) / GRID;   // >= 10 always

    // LOAD group (advance pointers), WRITE regs -> buffer wb
    #define LOADR() do { _Pragma("unroll") \
        for (int j = 0; j < 7; ++j) if (act[j]) { r[j] = *p[j]; p[j] += step[j]; } } while(0)
    #define WRITER(wb) do { _Pragma("unroll") \
        for (int j = 0; j < 7; ++j) if (act[j]) L4[(wb)*1680 + ldsoff[j]] = r[j]; } while(0)

    LOADR();                 // group bid -> regs
    WRITER(0);               // regs -> buf0 (compiler inserts vmcnt waits)
    if (niter > 1) LOADR();  // group bid+GRID -> regs (in flight over compute)
    __syncthreads();

    float lsum = 0.f;
    int cur = 0;

    for (int it = 0; it < niter; ++it) {
        const int g  = bid + it*GRID;
        const int nu = __builtin_amdgcn_readfirstlane(4*g + w);

        const float* Lb   = Lf + cur*6720;
        const float* sFF  = Lb + w*672;           // stride 28
        const float* sFS  = Lb + 2688 + w*288;    // stride 12
        const float* sFST = Lb + 3840 + w*288;    // stride 12
        const float* sSFT = Lb + 4992 + w*288;    // stride 24
        const float* sSS  = Lb + 6144 + w*144;    // stride 12

        // wave-uniform vectors -> scalar loads
        const float* vmpf = fmp + (size_t)nu*24;
        const float* vmff = fmf + (size_t)nu*24;
        const float* vmps = smp + (size_t)nu*12;
        const float* vmfs = smf + (size_t)nu*12;
        const float* vF   = f   + (size_t)nu*24;
        const float* vS   = s   + (size_t)nu*12;

        const bool isF    = lane < 32;
        const bool active = (lane < 24) | (lane >= 32 && lane < 44);
        const int gg = (lane < 24) ? lane : 23;
        const int tt = ((lane & 31) < 12) ? (lane & 31) : 11;

        float acc = 0.f;
        // P1: vfmp . {ff col g | fst col t}
        {
            const float* pp = isF ? (sFF + gg) : (sFST + tt);
            const int st    = isF ? 28 : 12;
            #pragma unroll
            for (int k = 0; k < 24; ++k) acc += vmpf[k] * pp[k*st];
        }
        // P2: {ff row g | sft row t} . vfmf   (b128)
        {
            const float4* q  = (const float4*)(isF ? (sFF + gg*28) : (sSFT + tt*24));
            const float4* v4 = (const float4*)vmff;
            #pragma unroll
            for (int k = 0; k < 6; ++k) {
                float4 a = q[k], b = v4[k];
                acc += a.x*b.x + a.y*b.y + a.z*b.z + a.w*b.w;
            }
        }
        // P3: vsmp . {sft col g | ss col t}
        {
            const float* pp = isF ? (sSFT + gg) : (sSS + tt);
            const int st    = isF ? 24 : 12;
            #pragma unroll
            for (int k = 0; k < 12; ++k) acc += vmps[k] * pp[k*st];
        }
        // P4: {fst row g | ss row t} . vsmf   (b128)
        {
            const float4* q  = (const float4*)(isF ? (sFST + gg*12) : (sSS + tt*12));
            const float4* v4 = (const float4*)vmfs;
            #pragma unroll
            for (int k = 0; k < 3; ++k) {
                float4 a = q[k], b = v4[k];
                acc += a.x*b.x + a.y*b.y + a.z*b.z + a.w*b.w;
            }
        }
        // P5: divergent
        if (isF) {
            const float4* q  = (const float4*)(sFS + gg*12);
            const float4* v4 = (const float4*)vS;
            #pragma unroll
            for (int k = 0; k < 3; ++k) {
                float4 a = q[k], b = v4[k];
                acc += a.x*b.x + a.y*b.y + a.z*b.z + a.w*b.w;
            }
        } else {
            const float* pp = sFS + tt;
            #pragma unroll
            for (int k = 0; k < 24; ++k) acc += vF[k] * pp[k*12];
        }

        float fval = 0.f;
        if (lane < 24)                    fval = vF[lane];
        else if (lane >= 32 && lane < 44) fval = vS[lane - 32];

        float nx = fval + 0.5f * acc;
        float xo = active ? fval : -INFINITY;
        float xn = active ? nx   : -INFINITY;

        float mo = segred_max(xo);
        float eo = expf(xo - mo);
        float so = segred_sum(eo);
        float lse_o = mo + logf(so);

        float mn = segred_max(xn);
        float en = expf(xn - mn);
        float sn = segred_sum(en);
        float pr = en / sn;
        float lse_n = mn + logf(sn);

        const size_t n = (size_t)nu;
        if (lane < 24)                    outf[n*24 + lane]        = pr;
        else if (lane >= 32 && lane < 44) outs[n*12 + (lane - 32)] = pr;

        const int fln = fl[nu], sln = sl[nu], yln = yl[nu];
        const int yfi = y2f[yln], ysi = y2s[yln];
        float lse_o_s = __shfl(lse_o, 32, 64);
        float lse_n_s = __shfl(lse_n, 32, 64);
        float vf_fl   = __shfl(xo, fln, 64);
        float vs_sl   = __shfl(xo, 32 + sln, 64);
        float nf_fl   = __shfl(xn, fln, 64);
        float ns_sl   = __shfl(xn, 32 + sln, 64);
        float vf_y    = __shfl(xo, yfi, 64);
        float vs_y    = __shfl(xo, 32 + ysi, 64);
        if (lane == 0) {
            float ce1 = lse_o   - vf_fl;
            float ce2 = lse_o_s - vs_sl;
            float stc = -expf(vf_y - lse_o) * expf(vs_y - lse_o_s);
            float ce3 = lse_n   - nf_fl;
            float ce4 = lse_n_s - ns_sl;
            lsum += ce1 + ce2 + stc + ce3 + ce4;
        }

        __syncthreads();                     // everyone done reading buf[cur]
        if (it + 1 < niter) {
            WRITER(cur ^ 1);                 // regs (group it+1) -> other buffer
            if (it + 2 < niter) LOADR();     // issue group it+2 loads
        }
        __syncthreads();                     // writes visible for next compute
        cur ^= 1;
    }

    if (lane == 0) part[bid*4 + w] = lsum;
    #undef LOADR
    #undef WRITER
}

// ---------------------------------------------------------------------------
// Kernel C: deterministic fixed-order loss reduction over GRID*4 partials.
// ---------------------------------------------------------------------------
__global__ void loss_reduce(const float* __restrict__ part, float* __restrict__ out) {
    __shared__ float sm[256];
    float a = 0.f;
    for (int i = threadIdx.x; i < GRID*4; i += 256) a += part[i];
    sm[threadIdx.x] = a;
    __syncthreads();
    for (int o = 128; o >= 1; o >>= 1) {
        if ((int)threadIdx.x < o) sm[threadIdx.x] += sm[threadIdx.x + o];
        __syncthreads();
    }
    if (threadIdx.x == 0) out[0] = sm[0] * (1.0f / (float)N_C);
}

extern "C" void kernel_launch(void* const* d_in, const int* in_sizes, int n_in,
                              void* d_out, int out_size, void* d_ws, size_t ws_size,
                              hipStream_t stream) {
    (void)in_sizes; (void)n_in; (void)out_size; (void)ws_size;

    const float* f   = (const float*)d_in[0];
    const float* s   = (const float*)d_in[1];
    const float* fs  = (const float*)d_in[2];
    const float* ff  = (const float*)d_in[3];
    const float* ss  = (const float*)d_in[4];
    const float* fst = (const float*)d_in[5];
    const float* sft = (const float*)d_in[6];
    const int* fl  = (const int*)d_in[7];
    const int* sl  = (const int*)d_in[8];
    const int* yl  = (const int*)d_in[9];
    const int* y2f = (const int*)d_in[11];
    const int* y2s = (const int*)d_in[12];

    float* ws   = (float*)d_ws;
    float* fmp  = ws;
    float* fmf  = fmp + (size_t)N_C * F_C;
    float* smp  = fmf + (size_t)N_C * F_C;
    float* smf  = smp + (size_t)N_C * S_C;
    float* part = smf + (size_t)N_C * S_C;   // GRID*4 partials

    float* outf = (float*)d_out;
    float* outs = outf + (size_t)N_C * F_C;
    float* outl = outs + (size_t)N_C * S_C;

    msg_kernel<<<(N_C * F_C) / 256, 256, 0, stream>>>(f, fmp, fmf, F_C);
    msg_kernel<<<(N_C * S_C) / 256, 256, 0, stream>>>(s, smp, smf, S_C);
    fuse_kernel<<<GRID, 256, 0, stream>>>(f, s, fs, ff, ss, fst, sft,
                                          fl, sl, yl, y2f, y2s,
                                          fmp, fmf, smp, smf,
                                          outf, outs, part);
    loss_reduce<<<1, 256, 0, stream>>>(part, outl);
}

// Round 4
// 89.228 us; speedup vs baseline: 1.8585x; 1.8585x over previous
//
#include <hip/hip_runtime.h>
#include <math.h>

#define L_C 1024
#define B_C 32
#define F_C 24
#define S_C 12
#define N_C (L_C*B_C)   // 32768
#define DWIN 20
#define GRID 768        // persistent: 3 blocks/CU (LDS-limited: 51.2 KB each)
#define NGRP (N_C/4)    // 8192 groups of 4 n (1 wave per n)
#define GRP_F4 1584     // f4 per group: FF 576 | FS 288 | FST 288 | SFT 288 | SS 144
#define BUF_F4 1600     // + 16 pad f4 for the staging tail

// ---------------------------------------------------------------------------
// Kernel A: windowed Gaussian message passing (tail beyond d=20 < 1e-21).
// ---------------------------------------------------------------------------
__global__ void msg_kernel(const float* __restrict__ x, float* __restrict__ mp,
                           float* __restrict__ mf, int C) {
    int idx = blockIdx.x * 256 + threadIdx.x;
    int stride = B_C * C;
    int total = N_C * C;
    if (idx >= total) return;
    int t = idx / stride;
    float accp = 0.f, accf = 0.f;
    #pragma unroll
    for (int d = 1; d <= DWIN; ++d) {
        float w = expf(-0.125f * (float)(d * d));
        if (t >= d)        accp += w * x[idx - d * stride];
        if (t + d < L_C)   accf += w * x[idx + d * stride];
    }
    mp[idx] = accp / fmaxf((float)t, 1.0f);
    mf[idx] = accf / fmaxf((float)(L_C - 1 - t), 1.0f);
}

__device__ inline float segred_max(float v) {
    #pragma unroll
    for (int o = 16; o >= 1; o >>= 1) v = fmaxf(v, __shfl_xor(v, o, 32));
    return v;
}
__device__ inline float segred_sum(float v) {
    #pragma unroll
    for (int o = 16; o >= 1; o >>= 1) v += __shfl_xor(v, o, 32);
    return v;
}

// ---------------------------------------------------------------------------
// Kernel B v4: persistent + double-buffered global_load_lds staging.
// HBM -> LDS direct (no VGPR data state, no scratch risk). Per group:
// 1584 f4 staged linearly; pad tail [1584,1600) gets duplicate bytes.
// Buffer layout (floats, per 6400-float buffer):
//   FF  [0,2304)      4n x (24x24), row stride 24
//   FS  [2304,3456)   4n x (24x12), row stride 12
//   FST [3456,4608)   4n x (24x12)
//   SFT [4608,5760)   4n x (12x24), row stride 24
//   SS  [5760,6336)   4n x (12x12)
// Pipeline: STAGE(next) issued BEFORE compute(cur); __syncthreads() at end
// of iter drains vmcnt (loads had the whole compute phase to land) + barrier.
// ---------------------------------------------------------------------------
__global__ __launch_bounds__(256, 3) void fuse_kernel(
    const float* __restrict__ f,  const float* __restrict__ s,
    const float* __restrict__ fs, const float* __restrict__ ff,
    const float* __restrict__ ss, const float* __restrict__ fst,
    const float* __restrict__ sft,
    const int* __restrict__ fl, const int* __restrict__ sl,
    const int* __restrict__ yl, const int* __restrict__ y2f,
    const int* __restrict__ y2s,
    const float* __restrict__ fmp, const float* __restrict__ fmf,
    const float* __restrict__ smp, const float* __restrict__ smf,
    float* __restrict__ outf, float* __restrict__ outs,
    float* __restrict__ part)
{
    __shared__ float4 L4[2*BUF_F4];   // 51200 B
    float* Lf = (float*)L4;
    char*  LB = (char*)L4;

    const int tid  = threadIdx.x;
    const int bid  = blockIdx.x;
    const int w    = tid >> 6;
    const int lane = tid & 63;

    // ---- per-thread staging sources: 7 NAMED pointer/stride pairs ----
    // (no arrays -> guaranteed registers, not scratch)
    const char *p0,*p1,*p2,*p3,*p4,*p5,*p6;
    int s0,s1,s2,s3,s4,s5,s6;
    {
        auto mk = [&](int j, const char*& P, int& S) {
            int i = tid + 256*j; if (i > GRP_F4-1) i = GRP_F4-1;  // clamp tail
            const float* base; int off, gsz;
            if (i < 576)       { base = ff;  off = i;        gsz = 576; }
            else if (i < 864)  { base = fs;  off = i - 576;  gsz = 288; }
            else if (i < 1152) { base = fst; off = i - 864;  gsz = 288; }
            else if (i < 1440) { base = sft; off = i - 1152; gsz = 288; }
            else               { base = ss;  off = i - 1440; gsz = 144; }
            P = (const char*)base + ((size_t)bid*gsz + off)*16;
            S = gsz * GRID * 16;
        };
        mk(0,p0,s0); mk(1,p1,s1); mk(2,p2,s2); mk(3,p3,s3);
        mk(4,p4,s4); mk(5,p5,s5); mk(6,p6,s6);
    }

    const int wbase = w*64*16;   // wave's lane-0 byte offset within a 256-f4 span

    #define ISSUE(J, PJ) \
        __builtin_amdgcn_global_load_lds( \
            (const __attribute__((address_space(1))) void*)(PJ), \
            (__attribute__((address_space(3))) void*)(LB + (co) + (J)*256*16 + wbase), \
            16, 0, 0)
    #define STAGE(coff) do { int co = (coff); \
        ISSUE(0,p0); ISSUE(1,p1); ISSUE(2,p2); \
        ISSUE(3,p3); ISSUE(4,p4); ISSUE(5,p5); \
        if (tid < 64) { ISSUE(6,p6); } \
        p0+=s0; p1+=s1; p2+=s2; p3+=s3; p4+=s4; p5+=s5; p6+=s6; \
    } while(0)

    const int niter = (NGRP - bid + GRID - 1) / GRID;

    STAGE(0);                  // group bid -> buf0
    __syncthreads();           // implicit vmcnt(0) drain + barrier

    float lsum = 0.f;
    int cur = 0;

    for (int it = 0; it < niter; ++it) {
        if (it + 1 < niter) STAGE((cur^1) * (BUF_F4*16));   // async, in flight over compute

        const int nu = __builtin_amdgcn_readfirstlane(4*(bid + it*GRID) + w);

        const float* Lb   = Lf + cur*(BUF_F4*4);
        const float* sFF  = Lb +        w*576;   // stride 24
        const float* sFS  = Lb + 2304 + w*288;   // stride 12
        const float* sFST = Lb + 3456 + w*288;   // stride 12
        const float* sSFT = Lb + 4608 + w*288;   // stride 24
        const float* sSS  = Lb + 5760 + w*144;   // stride 12

        // wave-uniform vectors -> scalar loads
        const float* vmpf = fmp + (size_t)nu*24;
        const float* vmff = fmf + (size_t)nu*24;
        const float* vmps = smp + (size_t)nu*12;
        const float* vmfs = smf + (size_t)nu*12;
        const float* vF   = f   + (size_t)nu*24;
        const float* vS   = s   + (size_t)nu*12;

        const bool isF    = lane < 32;
        const bool active = (lane < 24) | (lane >= 32 && lane < 44);
        const int gg = (lane < 24) ? lane : 23;
        const int tt = ((lane & 31) < 12) ? (lane & 31) : 11;

        float acc = 0.f;
        // P1: vfmp . {ff col g | fst col t}   (b32 cols: conflict-free)
        {
            const float* pp = isF ? (sFF + gg) : (sFST + tt);
            const int st    = isF ? 24 : 12;
            #pragma unroll
            for (int k = 0; k < 24; ++k) acc += vmpf[k] * pp[k*st];
        }
        // P2: {ff row g | sft row t} . vfmf   (b128 rows)
        {
            const float4* q  = (const float4*)(isF ? (sFF + gg*24) : (sSFT + tt*24));
            const float4* v4 = (const float4*)vmff;
            #pragma unroll
            for (int k = 0; k < 6; ++k) {
                float4 a = q[k], b = v4[k];
                acc += a.x*b.x + a.y*b.y + a.z*b.z + a.w*b.w;
            }
        }
        // P3: vsmp . {sft col g | ss col t}
        {
            const float* pp = isF ? (sSFT + gg) : (sSS + tt);
            const int st    = isF ? 24 : 12;
            #pragma unroll
            for (int k = 0; k < 12; ++k) acc += vmps[k] * pp[k*st];
        }
        // P4: {fst row g | ss row t} . vsmf   (b128)
        {
            const float4* q  = (const float4*)(isF ? (sFST + gg*12) : (sSS + tt*12));
            const float4* v4 = (const float4*)vmfs;
            #pragma unroll
            for (int k = 0; k < 3; ++k) {
                float4 a = q[k], b = v4[k];
                acc += a.x*b.x + a.y*b.y + a.z*b.z + a.w*b.w;
            }
        }
        // P5: divergent halves (different vectors)
        if (isF) {
            const float4* q  = (const float4*)(sFS + gg*12);
            const float4* v4 = (const float4*)vS;
            #pragma unroll
            for (int k = 0; k < 3; ++k) {
                float4 a = q[k], b = v4[k];
                acc += a.x*b.x + a.y*b.y + a.z*b.z + a.w*b.w;
            }
        } else {
            const float* pp = sFS + tt;
            #pragma unroll
            for (int k = 0; k < 24; ++k) acc += vF[k] * pp[k*12];
        }

        float fval = 0.f;
        if (lane < 24)                    fval = vF[lane];
        else if (lane >= 32 && lane < 44) fval = vS[lane - 32];

        float nx = fval + 0.5f * acc;
        float xo = active ? fval : -INFINITY;
        float xn = active ? nx   : -INFINITY;

        float mo = segred_max(xo);
        float eo = expf(xo - mo);
        float so = segred_sum(eo);
        float lse_o = mo + logf(so);

        float mn = segred_max(xn);
        float en = expf(xn - mn);
        float sn = segred_sum(en);
        float pr = en / sn;
        float lse_n = mn + logf(sn);

        const size_t n = (size_t)nu;
        if (lane < 24)                    outf[n*24 + lane]        = pr;
        else if (lane >= 32 && lane < 44) outs[n*12 + (lane - 32)] = pr;

        const int fln = fl[nu], sln = sl[nu], yln = yl[nu];
        const int yfi = y2f[yln], ysi = y2s[yln];
        float lse_o_s = __shfl(lse_o, 32, 64);
        float lse_n_s = __shfl(lse_n, 32, 64);
        float vf_fl   = __shfl(xo, fln, 64);
        float vs_sl   = __shfl(xo, 32 + sln, 64);
        float nf_fl   = __shfl(xn, fln, 64);
        float ns_sl   = __shfl(xn, 32 + sln, 64);
        float vf_y    = __shfl(xo, yfi, 64);
        float vs_y    = __shfl(xo, 32 + ysi, 64);
        if (lane == 0) {
            float ce1 = lse_o   - vf_fl;
            float ce2 = lse_o_s - vs_sl;
            float stc = -expf(vf_y - lse_o) * expf(vs_y - lse_o_s);
            float ce3 = lse_n   - nf_fl;
            float ce4 = lse_n_s - ns_sl;
            lsum += ce1 + ce2 + stc + ce3 + ce4;
        }

        __syncthreads();   // drains vmcnt(0) (stage complete) + barrier
        cur ^= 1;
    }

    if (lane == 0) part[bid*4 + w] = lsum;
    #undef STAGE
    #undef ISSUE
}

// ---------------------------------------------------------------------------
// Kernel C: deterministic fixed-order loss reduction over GRID*4 partials.
// ---------------------------------------------------------------------------
__global__ void loss_reduce(const float* __restrict__ part, float* __restrict__ out) {
    __shared__ float sm[256];
    float a = 0.f;
    for (int i = threadIdx.x; i < GRID*4; i += 256) a += part[i];
    sm[threadIdx.x] = a;
    __syncthreads();
    for (int o = 128; o >= 1; o >>= 1) {
        if ((int)threadIdx.x < o) sm[threadIdx.x] += sm[threadIdx.x + o];
        __syncthreads();
    }
    if (threadIdx.x == 0) out[0] = sm[0] * (1.0f / (float)N_C);
}

extern "C" void kernel_launch(void* const* d_in, const int* in_sizes, int n_in,
                              void* d_out, int out_size, void* d_ws, size_t ws_size,
                              hipStream_t stream) {
    (void)in_sizes; (void)n_in; (void)out_size; (void)ws_size;

    const float* f   = (const float*)d_in[0];
    const float* s   = (const float*)d_in[1];
    const float* fs  = (const float*)d_in[2];
    const float* ff  = (const float*)d_in[3];
    const float* ss  = (const float*)d_in[4];
    const float* fst = (const float*)d_in[5];
    const float* sft = (const float*)d_in[6];
    const int* fl  = (const int*)d_in[7];
    const int* sl  = (const int*)d_in[8];
    const int* yl  = (const int*)d_in[9];
    const int* y2f = (const int*)d_in[11];
    const int* y2s = (const int*)d_in[12];

    float* ws   = (float*)d_ws;
    float* fmp  = ws;
    float* fmf  = fmp + (size_t)N_C * F_C;
    float* smp  = fmf + (size_t)N_C * F_C;
    float* smf  = smp + (size_t)N_C * S_C;
    float* part = smf + (size_t)N_C * S_C;   // GRID*4 partials

    float* outf = (float*)d_out;
    float* outs = outf + (size_t)N_C * F_C;
    float* outl = outs + (size_t)N_C * S_C;

    msg_kernel<<<(N_C * F_C) / 256, 256, 0, stream>>>(f, fmp, fmf, F_C);
    msg_kernel<<<(N_C * S_C) / 256, 256, 0, stream>>>(s, smp, smf, S_C);
    fuse_kernel<<<GRID, 256, 0, stream>>>(f, s, fs, ff, ss, fst, sft,
                                          fl, sl, yl, y2f, y2s,
                                          fmp, fmf, smp, smf,
                                          outf, outs, part);
    loss_reduce<<<1, 256, 0, stream>>>(part, outl);
}